// Round 3
// baseline (66.944 us; speedup 1.0000x reference)
//
#include <hip/hip_runtime.h>

// ChamferDistance  B=16, N=M=4096, D=3, fp32 in/out (scalar out).
#define BQ     16
#define NPTS   4096
#define TOTAL  (BQ * NPTS)          // 65536 points per side
#define BLOCK  256
#define NPART  128

// scalar-B path geometry
#define APT    16                   // a-points per thread (registers)
#define ATILE  (BLOCK * APT)        // 4096 == NPTS (one batch per a-tile)
#define NATILE (TOTAL / ATILE)      // 16
#define MTILE  128
#define MT     (NPTS / MTILE)       // 32  -> grid 512 x 2

// fallback (LDS) path geometry — round-2 kernel
#define F_APT    8
#define F_ATILE  (BLOCK * F_APT)    // 2048
#define F_NATILE (TOTAL / F_ATILE)  // 32
#define F_MTILE  256
#define F_MT     (NPTS / F_MTILE)   // 16

// ws layout:
//   [0, 512K)            uint32 per-point min bits (dir0 then dir1)
//   [512K, 512K+2M)      float4 transformed points: [0,TOTAL)=p1', [TOTAL,2T)=p2'
//   [512K+2M, +512)      stage-1 partial sums
#define WS_MIN_BYTES ((size_t)2 * TOTAL * 4)
#define WS_T_BYTES   ((size_t)2 * TOTAL * 16)
#define WS_SCALAR_NEED (WS_MIN_BYTES + WS_T_BYTES + (size_t)NPART * 4)

__global__ __launch_bounds__(BLOCK) void cd_init_t(
        const float* __restrict__ p1, const float* __restrict__ p2,
        unsigned int* __restrict__ wsmin, float4* __restrict__ t) {
    const int i = blockIdx.x * BLOCK + threadIdx.x;       // [0, 2*TOTAL)
    wsmin[i] = 0x7F800000u;                               // +inf
    const float* src = (i < TOTAL) ? (p1 + (size_t)i * 3)
                                   : (p2 + (size_t)(i - TOTAL) * 3);
    const float x = src[0], y = src[1], z = src[2];
    t[i] = make_float4(-2.0f * x, -2.0f * y, -2.0f * z,
                       fmaf(x, x, fmaf(y, y, z * z)));
}

// Main kernel: B-side is wave-uniform -> s_load into SGPRs, no LDS at all.
__global__ __launch_bounds__(BLOCK) void cd_min_s(
        const float* __restrict__ p1, const float* __restrict__ p2,
        const float4* __restrict__ t, unsigned int* __restrict__ wsmin) {
    const int dir = blockIdx.y;
    const float* __restrict__ A = dir ? p2 : p1;          // register side (raw)
    const float4* __restrict__ B = dir ? t : (t + TOTAL); // scan side (transformed)
    unsigned int* __restrict__ outmin = wsmin + dir * TOTAL;

    const int atile = blockIdx.x / MT;                    // == batch (ATILE==NPTS)
    const int mtile = blockIdx.x % MT;
    const int a0 = atile * ATILE;
    const int m0 = atile * NPTS + mtile * MTILE;          // uniform across wave

    float ax[APT], ay[APT], az[APT], a2[APT], mn[APT];
#pragma unroll
    for (int k = 0; k < APT; ++k) {
        const int ai = a0 + k * BLOCK + threadIdx.x;
        const float* ap = A + (size_t)ai * 3;
        ax[k] = ap[0]; ay[k] = ap[1]; az[k] = ap[2];
        a2[k] = fmaf(ax[k], ax[k], fmaf(ay[k], ay[k], az[k] * az[k]));
        mn[k] = 3.0e38f;
    }

    // Per b-point: 1 v_mov (b.w -> VGPR) + APT*3 fma + APT/2 min3.
    // Uniform index m0+j  ->  s_load_dwordx4 on the SMEM pipe; zero LDS.
#pragma unroll 2
    for (int j = 0; j < MTILE; j += 2) {
        const float4 b0 = B[m0 + j];
        const float4 b1 = B[m0 + j + 1];
#pragma unroll
        for (int k = 0; k < APT; ++k) {
            float d0 = fmaf(az[k], b0.z, b0.w);
            d0 = fmaf(ay[k], b0.y, d0);
            d0 = fmaf(ax[k], b0.x, d0);
            float d1 = fmaf(az[k], b1.z, b1.w);
            d1 = fmaf(ay[k], b1.y, d1);
            d1 = fmaf(ax[k], b1.x, d1);
            float m;
            asm("v_min3_f32 %0, %1, %2, %3" : "=v"(m) : "v"(mn[k]), "v"(d0), "v"(d1));
            mn[k] = m;
        }
    }

#pragma unroll
    for (int k = 0; k < APT; ++k) {
        const int ai = a0 + k * BLOCK + threadIdx.x;
        atomicMin(&outmin[ai], __float_as_uint(fmaxf(a2[k] + mn[k], 0.0f)));
    }
}

// ---------------- fallback path (ws too small): round-2 LDS kernel ----------------
__global__ __launch_bounds__(BLOCK) void cd_init_ws(unsigned int* __restrict__ ws) {
    ws[blockIdx.x * BLOCK + threadIdx.x] = 0x7F800000u;
}

__global__ __launch_bounds__(BLOCK) void cd_min_lds(
        const float* __restrict__ p1, const float* __restrict__ p2,
        unsigned int* __restrict__ wsmin) {
    const int dir = blockIdx.y;
    const float* __restrict__ Aset = dir ? p2 : p1;
    const float* __restrict__ Bset = dir ? p1 : p2;
    unsigned int* __restrict__ outmin = wsmin + dir * TOTAL;

    const int atile = blockIdx.x / F_MT;
    const int mtile = blockIdx.x % F_MT;
    const int a0    = atile * F_ATILE;
    const int batch = a0 / NPTS;
    const int m0    = batch * NPTS + mtile * F_MTILE;

    __shared__ float4 sb[F_MTILE];
    {
        const int i = threadIdx.x;
        const float* bp = Bset + (size_t)(m0 + i) * 3;
        float bx = bp[0], by = bp[1], bz = bp[2];
        sb[i] = make_float4(-2.0f * bx, -2.0f * by, -2.0f * bz,
                            fmaf(bx, bx, fmaf(by, by, bz * bz)));
    }
    __syncthreads();

    float ax[F_APT], ay[F_APT], az[F_APT], a2[F_APT], mn[F_APT];
#pragma unroll
    for (int k = 0; k < F_APT; ++k) {
        const int ai = a0 + k * BLOCK + threadIdx.x;
        const float* ap = Aset + (size_t)ai * 3;
        ax[k] = ap[0]; ay[k] = ap[1]; az[k] = ap[2];
        a2[k] = fmaf(ax[k], ax[k], fmaf(ay[k], ay[k], az[k] * az[k]));
        mn[k] = 3.0e38f;
    }
#pragma unroll 2
    for (int j = 0; j < F_MTILE; j += 2) {
        const float4 b0 = sb[j];
        const float4 b1 = sb[j + 1];
#pragma unroll
        for (int k = 0; k < F_APT; ++k) {
            float d0 = fmaf(az[k], b0.z, b0.w);
            d0 = fmaf(ay[k], b0.y, d0);
            d0 = fmaf(ax[k], b0.x, d0);
            float d1 = fmaf(az[k], b1.z, b1.w);
            d1 = fmaf(ay[k], b1.y, d1);
            d1 = fmaf(ax[k], b1.x, d1);
            float m;
            asm("v_min3_f32 %0, %1, %2, %3" : "=v"(m) : "v"(mn[k]), "v"(d0), "v"(d1));
            mn[k] = m;
        }
    }
#pragma unroll
    for (int k = 0; k < F_APT; ++k) {
        const int ai = a0 + k * BLOCK + threadIdx.x;
        atomicMin(&outmin[ai], __float_as_uint(fmaxf(a2[k] + mn[k], 0.0f)));
    }
}

// ---------------- deterministic sum ----------------
__global__ __launch_bounds__(BLOCK) void cd_reduce1(const float* __restrict__ wsmin,
                                                    float* __restrict__ partial) {
    __shared__ float sred[BLOCK];
    const float4* __restrict__ v = (const float4*)wsmin;
    const int i = blockIdx.x * BLOCK + threadIdx.x;       // 128*256 == 2*TOTAL/4
    float4 x = v[i];
    sred[threadIdx.x] = (x.x + x.y) + (x.z + x.w);
    __syncthreads();
    for (int st = BLOCK / 2; st > 0; st >>= 1) {
        if (threadIdx.x < st) sred[threadIdx.x] += sred[threadIdx.x + st];
        __syncthreads();
    }
    if (threadIdx.x == 0) partial[blockIdx.x] = sred[0];
}

__global__ __launch_bounds__(NPART) void cd_reduce2(const float* __restrict__ partial,
                                                    float* __restrict__ out) {
    __shared__ float sred[NPART];
    sred[threadIdx.x] = partial[threadIdx.x];
    __syncthreads();
    for (int st = NPART / 2; st > 0; st >>= 1) {
        if (threadIdx.x < st) sred[threadIdx.x] += sred[threadIdx.x + st];
        __syncthreads();
    }
    if (threadIdx.x == 0) out[0] = sred[0] * (1.0f / (float)BQ);
}

__global__ __launch_bounds__(1024) void cd_reduce_single(const float* __restrict__ wsmin,
                                                         float* __restrict__ out) {
    __shared__ float sred[1024];
    const float4* __restrict__ v = (const float4*)wsmin;
    float s = 0.0f;
    for (int i = threadIdx.x; i < (2 * TOTAL) / 4; i += 1024) {
        float4 x = v[i];
        s += (x.x + x.y) + (x.z + x.w);
    }
    sred[threadIdx.x] = s;
    __syncthreads();
    for (int st = 512; st > 0; st >>= 1) {
        if (threadIdx.x < st) sred[threadIdx.x] += sred[threadIdx.x + st];
        __syncthreads();
    }
    if (threadIdx.x == 0) out[0] = sred[0] * (1.0f / (float)BQ);
}

extern "C" void kernel_launch(void* const* d_in, const int* in_sizes, int n_in,
                              void* d_out, int out_size, void* d_ws, size_t ws_size,
                              hipStream_t stream) {
    const float* p1 = (const float*)d_in[0];
    const float* p2 = (const float*)d_in[1];
    float* out = (float*)d_out;
    unsigned int* wsmin = (unsigned int*)d_ws;
    float4* t = (float4*)((char*)d_ws + WS_MIN_BYTES);
    float* partial = (float*)((char*)d_ws + WS_MIN_BYTES + WS_T_BYTES);

    if (ws_size >= WS_SCALAR_NEED) {
        cd_init_t<<<(2 * TOTAL) / BLOCK, BLOCK, 0, stream>>>(p1, p2, wsmin, t);
        dim3 grid(NATILE * MT, 2, 1);                     // 512 x 2
        cd_min_s<<<grid, BLOCK, 0, stream>>>(p1, p2, t, wsmin);
        cd_reduce1<<<NPART, BLOCK, 0, stream>>>((const float*)wsmin, partial);
        cd_reduce2<<<1, NPART, 0, stream>>>(partial, out);
    } else if (ws_size >= WS_MIN_BYTES + NPART * 4) {
        cd_init_ws<<<(2 * TOTAL) / BLOCK, BLOCK, 0, stream>>>(wsmin);
        dim3 grid(F_NATILE * F_MT, 2, 1);
        cd_min_lds<<<grid, BLOCK, 0, stream>>>(p1, p2, wsmin);
        cd_reduce1<<<NPART, BLOCK, 0, stream>>>((const float*)wsmin,
                                                (float*)((char*)d_ws + WS_MIN_BYTES));
        cd_reduce2<<<1, NPART, 0, stream>>>((float*)((char*)d_ws + WS_MIN_BYTES), out);
    } else {
        cd_init_ws<<<(2 * TOTAL) / BLOCK, BLOCK, 0, stream>>>(wsmin);
        dim3 grid(F_NATILE * F_MT, 2, 1);
        cd_min_lds<<<grid, BLOCK, 0, stream>>>(p1, p2, wsmin);
        cd_reduce_single<<<1, 1024, 0, stream>>>((const float*)wsmin, out);
    }
}

// Round 4
// 53.099 us; speedup vs baseline: 1.2608x; 1.2608x over previous
//
#include <hip/hip_runtime.h>

// ChamferDistance  B=16, N=M=4096, D=3, fp32 in/out (scalar out).
#define BQ     16
#define NPTS   4096
#define TOTAL  (BQ * NPTS)          // 65536 points per side
#define BLOCK  256
#define NPART  128

#define APT    16                   // a-points per thread (registers)
#define ATILE  (BLOCK * APT)        // 4096 == NPTS (one batch per a-tile)
#define NATILE (TOTAL / ATILE)      // 16
#define MTILE  128                  // b-points staged in LDS per block
#define MT     (NPTS / MTILE)       // 32  -> grid 512 x 2 = 1024 blocks (4/CU)

// ws layout:
//   [0, 512K)       uint32 per-point min bits (dir0 then dir1)
//   [512K, +512B)   stage-1 partial sums
#define WS_MIN_BYTES ((size_t)2 * TOTAL * 4)

__global__ __launch_bounds__(BLOCK) void cd_init_ws(unsigned int* __restrict__ ws) {
    ws[blockIdx.x * BLOCK + threadIdx.x] = 0x7F800000u;   // +inf
}

__global__ __launch_bounds__(BLOCK, 4) void cd_min_kernel(
        const float* __restrict__ p1, const float* __restrict__ p2,
        unsigned int* __restrict__ wsmin) {
    const int dir = blockIdx.y;
    const float* __restrict__ Aset = dir ? p2 : p1;   // side kept in registers
    const float* __restrict__ Bset = dir ? p1 : p2;   // side scanned from LDS
    unsigned int* __restrict__ outmin = wsmin + dir * TOTAL;

    const int atile = blockIdx.x / MT;                // == batch (ATILE == NPTS)
    const int mtile = blockIdx.x % MT;
    const int a0    = atile * ATILE;
    const int m0    = atile * NPTS + mtile * MTILE;

    // Stage b-tile as (-2bx, -2by, -2bz, |b|^2); a2 folded in after the min.
    __shared__ float4 sb[MTILE];
    for (int i = threadIdx.x; i < MTILE; i += BLOCK) {
        const float* bp = Bset + (size_t)(m0 + i) * 3;
        float bx = bp[0], by = bp[1], bz = bp[2];
        sb[i] = make_float4(-2.0f * bx, -2.0f * by, -2.0f * bz,
                            fmaf(bx, bx, fmaf(by, by, bz * bz)));
    }
    __syncthreads();

    float ax[APT], ay[APT], az[APT], a2[APT], mn[APT];
#pragma unroll
    for (int k = 0; k < APT; ++k) {
        const int ai = a0 + k * BLOCK + threadIdx.x;
        const float* ap = Aset + (size_t)ai * 3;
        ax[k] = ap[0]; ay[k] = ap[1]; az[k] = ap[2];
        a2[k] = fmaf(ax[k], ax[k], fmaf(ay[k], ay[k], az[k] * az[k]));
        mn[k] = 3.0e38f;
    }

    // 2 b-points per step; 3 fma + 1/2 v_min3 per pair = 3.5 VALU ops/pair.
    auto pair2 = [&](const float4& b0, const float4& b1) {
#pragma unroll
        for (int k = 0; k < APT; ++k) {
            float d0 = fmaf(az[k], b0.z, b0.w);
            d0 = fmaf(ay[k], b0.y, d0);
            d0 = fmaf(ax[k], b0.x, d0);
            float d1 = fmaf(az[k], b1.z, b1.w);
            d1 = fmaf(ay[k], b1.y, d1);
            d1 = fmaf(ax[k], b1.x, d1);
            asm("v_min3_f32 %0, %1, %2, %3"
                : "=v"(mn[k]) : "v"(mn[k]), "v"(d0), "v"(d1));
        }
    };

    // Software pipeline: prefetch next 2 b-points into registers BEFORE the
    // ~224-cycle compute on the current 2, so ds_read latency is hidden and
    // the wave never stalls on lgkmcnt (R2's 50% VALU duty bug).
    float4 c0 = sb[0], c1 = sb[1];
#pragma unroll 2
    for (int j = 0; j < MTILE - 2; j += 2) {
        float4 n0 = sb[j + 2];
        float4 n1 = sb[j + 3];
        pair2(c0, c1);
        c0 = n0; c1 = n1;
    }
    pair2(c0, c1);

    // a2 added once per a-point; clamp >=0 so uint ordering == float ordering.
#pragma unroll
    for (int k = 0; k < APT; ++k) {
        const int ai = a0 + k * BLOCK + threadIdx.x;
        atomicMin(&outmin[ai], __float_as_uint(fmaxf(a2[k] + mn[k], 0.0f)));
    }
}

// ---------------- deterministic sum ----------------
__global__ __launch_bounds__(BLOCK) void cd_reduce1(const float* __restrict__ wsmin,
                                                    float* __restrict__ partial) {
    __shared__ float sred[BLOCK];
    const float4* __restrict__ v = (const float4*)wsmin;
    const int i = blockIdx.x * BLOCK + threadIdx.x;   // 128*256 == 2*TOTAL/4
    float4 x = v[i];
    sred[threadIdx.x] = (x.x + x.y) + (x.z + x.w);
    __syncthreads();
    for (int st = BLOCK / 2; st > 0; st >>= 1) {
        if (threadIdx.x < st) sred[threadIdx.x] += sred[threadIdx.x + st];
        __syncthreads();
    }
    if (threadIdx.x == 0) partial[blockIdx.x] = sred[0];
}

__global__ __launch_bounds__(NPART) void cd_reduce2(const float* __restrict__ partial,
                                                    float* __restrict__ out) {
    __shared__ float sred[NPART];
    sred[threadIdx.x] = partial[threadIdx.x];
    __syncthreads();
    for (int st = NPART / 2; st > 0; st >>= 1) {
        if (threadIdx.x < st) sred[threadIdx.x] += sred[threadIdx.x + st];
        __syncthreads();
    }
    if (threadIdx.x == 0) out[0] = sred[0] * (1.0f / (float)BQ);
}

__global__ __launch_bounds__(1024) void cd_reduce_single(const float* __restrict__ wsmin,
                                                         float* __restrict__ out) {
    __shared__ float sred[1024];
    const float4* __restrict__ v = (const float4*)wsmin;
    float s = 0.0f;
    for (int i = threadIdx.x; i < (2 * TOTAL) / 4; i += 1024) {
        float4 x = v[i];
        s += (x.x + x.y) + (x.z + x.w);
    }
    sred[threadIdx.x] = s;
    __syncthreads();
    for (int st = 512; st > 0; st >>= 1) {
        if (threadIdx.x < st) sred[threadIdx.x] += sred[threadIdx.x + st];
        __syncthreads();
    }
    if (threadIdx.x == 0) out[0] = sred[0] * (1.0f / (float)BQ);
}

extern "C" void kernel_launch(void* const* d_in, const int* in_sizes, int n_in,
                              void* d_out, int out_size, void* d_ws, size_t ws_size,
                              hipStream_t stream) {
    const float* p1 = (const float*)d_in[0];
    const float* p2 = (const float*)d_in[1];
    float* out = (float*)d_out;
    unsigned int* wsmin = (unsigned int*)d_ws;        // 512 KiB
    float* partial = (float*)((char*)d_ws + WS_MIN_BYTES);

    cd_init_ws<<<(2 * TOTAL) / BLOCK, BLOCK, 0, stream>>>(wsmin);

    dim3 grid(NATILE * MT, 2, 1);                     // 512 x 2 = 1024 blocks
    cd_min_kernel<<<grid, BLOCK, 0, stream>>>(p1, p2, wsmin);

    if (ws_size >= WS_MIN_BYTES + (size_t)NPART * 4) {
        cd_reduce1<<<NPART, BLOCK, 0, stream>>>((const float*)wsmin, partial);
        cd_reduce2<<<1, NPART, 0, stream>>>(partial, out);
    } else {
        cd_reduce_single<<<1, 1024, 0, stream>>>((const float*)wsmin, out);
    }
}

// Round 5
// 48.259 us; speedup vs baseline: 1.3872x; 1.1003x over previous
//
#include <hip/hip_runtime.h>

// ChamferDistance  B=16, N=M=4096, D=3, fp32 in/out (scalar out).
// MFMA formulation: d(a,b) = sum_k A[k]*B[k] over 13 bf16 hi/lo slots (K=16).
#define BQ     16
#define NPTS   4096
#define TOTAL  (BQ * NPTS)          // 65536 points per side
#define NPART  128

#define WS_MIN_BYTES ((size_t)2 * TOTAL * 4)            // 512 KiB (uint min bits)
#define PANEL_BYTES  ((size_t)(TOTAL / 32) * 64 * 16)   // 2048 tiles * 1 KiB = 2 MiB
#define WS_NEED      (WS_MIN_BYTES + PANEL_BYTES + (size_t)NPART * 4)

typedef __attribute__((ext_vector_type(8)))  short short8;
typedef __attribute__((ext_vector_type(16))) float f32x16;

__device__ __forceinline__ unsigned short f2bf(float x) {
    union { float f; unsigned u; } v; v.f = x;
    unsigned r = v.u + 0x7FFFu + ((v.u >> 16) & 1u);    // RNE
    return (unsigned short)(r >> 16);
}
__device__ __forceinline__ float bf2f(unsigned short h) {
    union { float f; unsigned u; } v; v.u = ((unsigned)h) << 16; return v.f;
}

// B-role slots, k = 8*g + j (any fixed A==B k-map works; sum is perm-invariant):
//  k0-2: -2bH(xyz)  k3-5: -2bL(xyz)  k6-8: -2bH(xyz again)  k9,10: 1,1
//  k11,12: b2H,b2L  k13-15: 0
__device__ __forceinline__ uint4 make_bslots(const float* __restrict__ pts,
                                             int tile, int lane) {
    const int pidx = lane & 31, g = lane >> 5;
    const float* pp = pts + (size_t)(tile * 32 + pidx) * 3;
    const float x = pp[0], y = pp[1], z = pp[2];
    const unsigned short xh = f2bf(x), yh = f2bf(y), zh = f2bf(z);
    const unsigned short xl = f2bf(x - bf2f(xh)), yl = f2bf(y - bf2f(yh)),
                         zl = f2bf(z - bf2f(zh));
    const unsigned short m2xh = f2bf(-2.0f * bf2f(xh)), m2yh = f2bf(-2.0f * bf2f(yh)),
                         m2zh = f2bf(-2.0f * bf2f(zh));
    const unsigned short m2xl = f2bf(-2.0f * bf2f(xl)), m2yl = f2bf(-2.0f * bf2f(yl)),
                         m2zl = f2bf(-2.0f * bf2f(zl));
    const float s2 = fmaf(x, x, fmaf(y, y, z * z));
    const unsigned short s2h = f2bf(s2);
    const unsigned short s2l = f2bf(s2 - bf2f(s2h));
    const unsigned short ONE = 0x3F80;
    unsigned short s[8];
    if (g == 0) { s[0]=m2xh; s[1]=m2yh; s[2]=m2zh; s[3]=m2xl; s[4]=m2yl; s[5]=m2zl; s[6]=m2xh; s[7]=m2yh; }
    else        { s[0]=m2zh; s[1]=ONE;  s[2]=ONE;  s[3]=s2h;  s[4]=s2l;  s[5]=0;    s[6]=0;    s[7]=0;   }
    uint4 o;
    o.x = (unsigned)s[0] | ((unsigned)s[1] << 16);
    o.y = (unsigned)s[2] | ((unsigned)s[3] << 16);
    o.z = (unsigned)s[4] | ((unsigned)s[5] << 16);
    o.w = (unsigned)s[6] | ((unsigned)s[7] << 16);
    return o;
}

// A-role slots (paired with B above): k0-2 aH, k3-5 aH, k6-8 aL, k9 a2H,
// k10 a2L, k11,12: 1,1, k13-15: 0.
__device__ __forceinline__ short8 make_aslots(const float* __restrict__ pts,
                                              int point, int g) {
    const float* pp = pts + (size_t)point * 3;
    const float x = pp[0], y = pp[1], z = pp[2];
    const unsigned short xh = f2bf(x), yh = f2bf(y), zh = f2bf(z);
    const unsigned short xl = f2bf(x - bf2f(xh)), yl = f2bf(y - bf2f(yh)),
                         zl = f2bf(z - bf2f(zh));
    const float s2 = fmaf(x, x, fmaf(y, y, z * z));
    const unsigned short s2h = f2bf(s2);
    const unsigned short s2l = f2bf(s2 - bf2f(s2h));
    const unsigned short ONE = 0x3F80;
    unsigned short s[8];
    if (g == 0) { s[0]=xh; s[1]=yh; s[2]=zh; s[3]=xh; s[4]=yh; s[5]=zh; s[6]=xl; s[7]=yl; }
    else        { s[0]=zl; s[1]=s2h; s[2]=s2l; s[3]=ONE; s[4]=ONE; s[5]=0; s[6]=0; s[7]=0; }
    union { unsigned u[4]; short8 v; } o;
    o.u[0] = (unsigned)s[0] | ((unsigned)s[1] << 16);
    o.u[1] = (unsigned)s[2] | ((unsigned)s[3] << 16);
    o.u[2] = (unsigned)s[4] | ((unsigned)s[5] << 16);
    o.u[3] = (unsigned)s[6] | ((unsigned)s[7] << 16);
    return o.v;
}

// init wsmin (+inf) AND build panel for side `pts` — one thread per (point,group)
__global__ __launch_bounds__(256) void cd_init_prep(const float* __restrict__ pts,
        unsigned* __restrict__ wsmin, uint4* __restrict__ panel) {
    const int tid = blockIdx.x * 256 + threadIdx.x;   // [0, 131072) == 2*TOTAL
    wsmin[tid] = 0x7F800000u;
    panel[tid] = make_bslots(pts, tid >> 6, tid & 63);
}

__global__ __launch_bounds__(256) void cd_prep(const float* __restrict__ pts,
                                               uint4* __restrict__ panel) {
    const int tid = blockIdx.x * 256 + threadIdx.x;
    panel[tid] = make_bslots(pts, tid >> 6, tid & 63);
}

// Main: block = 2 waves x 64 rows = 128 rows, sweeps 64 col-tiles (half batch).
// grid = 16 batches * 32 rowblocks * 2 colhalves = 1024 blocks.
#define MAIN_BLOCK 128
#define CHUNK 8
__global__ __launch_bounds__(MAIN_BLOCK, 2) void cd_mfma(
        const float* __restrict__ Aset, const uint4* __restrict__ panel,
        unsigned* __restrict__ outmin) {
    const int bx   = blockIdx.x;
    const int b    = bx >> 6;
    const int rb   = (bx >> 1) & 31;
    const int ch   = bx & 1;
    const int wave = threadIdx.x >> 6;
    const int lane = threadIdx.x & 63;
    const int pidx = lane & 31, g = lane >> 5;

    const int rowbase = b * NPTS + rb * 128 + wave * 64;

    const short8 a0 = make_aslots(Aset, rowbase + pidx, g);
    const short8 a1 = make_aslots(Aset, rowbase + 32 + pidx, g);

    f32x16 zero, r0, r1;
#pragma unroll
    for (int e = 0; e < 16; ++e) { zero[e] = 0.0f; r0[e] = 3.0e38f; r1[e] = 3.0e38f; }

    __shared__ uint4 sb[CHUNK * 64];                  // 8 KiB: 8 col-tile fragments
    const uint4* pbase = panel + ((size_t)(b * 128 + ch * 64) * 64);

    for (int c = 0; c < 64 / CHUNK; ++c) {
        __syncthreads();
#pragma unroll
        for (int i = 0; i < 4; ++i) {
            const int idx = threadIdx.x + i * MAIN_BLOCK;
            sb[idx] = pbase[c * (CHUNK * 64) + idx];
        }
        __syncthreads();
#pragma unroll
        for (int t = 0; t < CHUNK; ++t) {
            const short8 bf = *reinterpret_cast<const short8*>(&sb[t * 64 + lane]);
            f32x16 d0 = __builtin_amdgcn_mfma_f32_32x32x16_bf16(a0, bf, zero, 0, 0, 0);
            f32x16 d1 = __builtin_amdgcn_mfma_f32_32x32x16_bf16(a1, bf, zero, 0, 0, 0);
#pragma unroll
            for (int e = 0; e < 16; ++e) r0[e] = fminf(r0[e], d0[e]);
#pragma unroll
            for (int e = 0; e < 16; ++e) r1[e] = fminf(r1[e], d1[e]);
        }
    }

    // Reduce across 32 columns (lanes sharing g-half), then one atomic per row.
    // D layout (m74/m101): col = lane&31, row = (r&3) + 8*(r>>2) + 4*g.
#pragma unroll
    for (int r = 0; r < 16; ++r) {
        float v0 = r0[r], v1 = r1[r];
#pragma unroll
        for (int m = 1; m <= 16; m <<= 1) {
            v0 = fminf(v0, __shfl_xor(v0, m));
            v1 = fminf(v1, __shfl_xor(v1, m));
        }
        const int rl = (r & 3) + 8 * (r >> 2) + 4 * g;
        if (pidx == 0) {
            atomicMin(&outmin[rowbase + rl],      __float_as_uint(fmaxf(v0, 0.0f)));
            atomicMin(&outmin[rowbase + 32 + rl], __float_as_uint(fmaxf(v1, 0.0f)));
        }
    }
}

// ---------------- deterministic sum ----------------
__global__ __launch_bounds__(256) void cd_reduce1(const float* __restrict__ wsmin,
                                                  float* __restrict__ partial) {
    __shared__ float sred[256];
    const float4* __restrict__ v = (const float4*)wsmin;
    const int i = blockIdx.x * 256 + threadIdx.x;     // 128*256 == 2*TOTAL/4
    float4 x = v[i];
    sred[threadIdx.x] = (x.x + x.y) + (x.z + x.w);
    __syncthreads();
    for (int st = 128; st > 0; st >>= 1) {
        if (threadIdx.x < st) sred[threadIdx.x] += sred[threadIdx.x + st];
        __syncthreads();
    }
    if (threadIdx.x == 0) partial[blockIdx.x] = sred[0];
}

__global__ __launch_bounds__(NPART) void cd_reduce2(const float* __restrict__ partial,
                                                    float* __restrict__ out) {
    __shared__ float sred[NPART];
    sred[threadIdx.x] = partial[threadIdx.x];
    __syncthreads();
    for (int st = NPART / 2; st > 0; st >>= 1) {
        if (threadIdx.x < st) sred[threadIdx.x] += sred[threadIdx.x + st];
        __syncthreads();
    }
    if (threadIdx.x == 0) out[0] = sred[0] * (1.0f / (float)BQ);
}

// ---------------- fallback (ws too small): R2 LDS-scalar path ----------------
__global__ __launch_bounds__(256) void cd_init_ws(unsigned int* __restrict__ ws) {
    ws[blockIdx.x * 256 + threadIdx.x] = 0x7F800000u;
}
#define F_APT 8
__global__ __launch_bounds__(256) void cd_min_lds(
        const float* __restrict__ p1, const float* __restrict__ p2,
        unsigned int* __restrict__ wsmin) {
    const int dir = blockIdx.y;
    const float* __restrict__ Aset = dir ? p2 : p1;
    const float* __restrict__ Bset = dir ? p1 : p2;
    unsigned int* __restrict__ outmin = wsmin + dir * TOTAL;
    const int atile = blockIdx.x / 16;
    const int mtile = blockIdx.x % 16;
    const int a0 = atile * 2048;
    const int m0 = (a0 / NPTS) * NPTS + mtile * 256;
    __shared__ float4 sbf[256];
    {
        const float* bp = Bset + (size_t)(m0 + threadIdx.x) * 3;
        float bx = bp[0], by = bp[1], bz = bp[2];
        sbf[threadIdx.x] = make_float4(-2.0f*bx, -2.0f*by, -2.0f*bz,
                                       fmaf(bx,bx,fmaf(by,by,bz*bz)));
    }
    __syncthreads();
    float ax[F_APT], ay[F_APT], az[F_APT], a2[F_APT], mn[F_APT];
#pragma unroll
    for (int k = 0; k < F_APT; ++k) {
        const int ai = a0 + k*256 + threadIdx.x;
        const float* ap = Aset + (size_t)ai * 3;
        ax[k]=ap[0]; ay[k]=ap[1]; az[k]=ap[2];
        a2[k]=fmaf(ax[k],ax[k],fmaf(ay[k],ay[k],az[k]*az[k]));
        mn[k]=3.0e38f;
    }
#pragma unroll 2
    for (int j = 0; j < 256; j += 2) {
        const float4 b0 = sbf[j], b1 = sbf[j+1];
#pragma unroll
        for (int k = 0; k < F_APT; ++k) {
            float d0 = fmaf(az[k],b0.z,b0.w); d0=fmaf(ay[k],b0.y,d0); d0=fmaf(ax[k],b0.x,d0);
            float d1 = fmaf(az[k],b1.z,b1.w); d1=fmaf(ay[k],b1.y,d1); d1=fmaf(ax[k],b1.x,d1);
            asm("v_min3_f32 %0, %1, %2, %3" : "=v"(mn[k]) : "v"(mn[k]), "v"(d0), "v"(d1));
        }
    }
#pragma unroll
    for (int k = 0; k < F_APT; ++k) {
        const int ai = a0 + k*256 + threadIdx.x;
        atomicMin(&outmin[ai], __float_as_uint(fmaxf(a2[k]+mn[k], 0.0f)));
    }
}
__global__ __launch_bounds__(1024) void cd_reduce_single(const float* __restrict__ wsmin,
                                                         float* __restrict__ out) {
    __shared__ float sred[1024];
    const float4* __restrict__ v = (const float4*)wsmin;
    float s = 0.0f;
    for (int i = threadIdx.x; i < (2*TOTAL)/4; i += 1024) {
        float4 x = v[i]; s += (x.x + x.y) + (x.z + x.w);
    }
    sred[threadIdx.x] = s;
    __syncthreads();
    for (int st = 512; st > 0; st >>= 1) {
        if (threadIdx.x < st) sred[threadIdx.x] += sred[threadIdx.x + st];
        __syncthreads();
    }
    if (threadIdx.x == 0) out[0] = sred[0] * (1.0f / (float)BQ);
}

extern "C" void kernel_launch(void* const* d_in, const int* in_sizes, int n_in,
                              void* d_out, int out_size, void* d_ws, size_t ws_size,
                              hipStream_t stream) {
    const float* p1 = (const float*)d_in[0];
    const float* p2 = (const float*)d_in[1];
    float* out = (float*)d_out;
    unsigned* wsmin = (unsigned*)d_ws;
    uint4* panel = (uint4*)((char*)d_ws + WS_MIN_BYTES);
    float* partial = (float*)((char*)d_ws + WS_MIN_BYTES + PANEL_BYTES);

    if (ws_size >= WS_NEED) {
        // pass 1: dir0 (A = p1 rows, B-role panel from p2)
        cd_init_prep<<<512, 256, 0, stream>>>(p2, wsmin, panel);
        cd_mfma<<<1024, MAIN_BLOCK, 0, stream>>>(p1, panel, wsmin);
        // pass 2: dir1 (A = p2 rows, B-role panel rebuilt from p1)
        cd_prep<<<512, 256, 0, stream>>>(p1, panel);
        cd_mfma<<<1024, MAIN_BLOCK, 0, stream>>>(p2, panel, wsmin + TOTAL);
        cd_reduce1<<<128, 256, 0, stream>>>((const float*)wsmin, partial);
        cd_reduce2<<<1, NPART, 0, stream>>>(partial, out);
    } else {
        cd_init_ws<<<(2 * TOTAL) / 256, 256, 0, stream>>>(wsmin);
        dim3 grid(512, 2, 1);
        cd_min_lds<<<grid, 256, 0, stream>>>(p1, p2, wsmin);
        cd_reduce_single<<<1, 1024, 0, stream>>>((const float*)wsmin, out);
    }
}